// Round 21
// baseline (150.017 us; speedup 1.0000x reference)
//
#include <hip/hip_runtime.h>
#include <hip/hip_bf16.h>

// GCN regression: out = relu( dinv⊙(A_hat @ (dinv⊙(x@W1^T))) + b1 ) @ W2^T + b2
// R16: 128-node buckets (NB=782 -> 2x blocks in csr-sort), gemm standalone
//      with in-kernel W1 cvt, memset for bcnt. 4 dispatches + memset.
//   1. part_kernel : per-block(4096 edges) LDS hist + scan + 1 atomic/bucket
//                    -> slotted ebuf (bucket b at b*CAPB)
//   2. csrb_kernel : per-bucket(128 nodes) node hist+scan (offs/degc),
//                    LDS scatter -> node-sorted csr IN PLACE over ebuf
//   3. gemm_kernel : g = dinv ⊙ (x @ W1^T) via mfma_f32_16x16x32_bf16
//   4. agg_kernel  : wave per node; s_load csr indices; 16 gathers in flight

typedef unsigned int u32;
typedef unsigned short u16;
typedef __attribute__((ext_vector_type(8))) short bf16x8;
typedef __attribute__((ext_vector_type(4))) float f32x4;

#define PK 4096      // edges per partition block
#define PTH 512      // part threads
#define EPT (PK/PTH) // 8
#define NBMAX 1024   // padded bucket-array size (NB=782)
#define CAPB 4864    // slot capacity per 128-node bucket (mean 4092, +12 sigma)

__device__ __forceinline__ short f2bf(float f) {   // RNE via hardware cvt
    __hip_bfloat16 h = __float2bfloat16(f);
    return *reinterpret_cast<short*>(&h);
}
__device__ __forceinline__ float bf2f(u16 u) {
    return __uint_as_float(((u32)u) << 16);
}
__device__ __forceinline__ bf16x8 pack8(float4 lo, float4 hi) {
    bf16x8 o;
    o[0] = f2bf(lo.x); o[1] = f2bf(lo.y); o[2] = f2bf(lo.z); o[3] = f2bf(lo.w);
    o[4] = f2bf(hi.x); o[5] = f2bf(hi.y); o[6] = f2bf(hi.z); o[7] = f2bf(hi.w);
    return o;
}

// ---- 1. chunked partition -> slotted ebuf (128-node buckets) ----
__global__ __launch_bounds__(PTH) void part_kernel(const int* __restrict__ src,
                                                   const int* __restrict__ dst,
                                                   int* __restrict__ bcnt,
                                                   u32* __restrict__ ebuf, int E, int NB) {
    __shared__ u32 stage[PK];     // 16 KB
    __shared__ u16 sbid[PK];      // 8 KB
    __shared__ int h[NBMAX], loff[NBMAX], gbase[NBMAX], cur[NBMAX];   // 16 KB
    int t = threadIdx.x;
    int e0 = blockIdx.x * PK;
    int e1 = e0 + PK; if (e1 > E) e1 = E;
    int cnt = e1 - e0;
    for (int i = t; i < NBMAX; i += PTH) { h[i] = 0; cur[i] = 0; }
    __syncthreads();
    int dreg[EPT];
#pragma unroll
    for (int i = 0; i < EPT; ++i) {
        int e = e0 + i * PTH + t;
        dreg[i] = (e < e1) ? dst[e] : -1;
        if (dreg[i] >= 0) atomicAdd(&h[dreg[i] >> 7], 1);
    }
    __syncthreads();
    if (t < 64) {                 // wave 0: scan 1024 slots, carry across chunks
        int carry = 0;
        for (int c = 0; c < 16; ++c) {
            int idx = c * 64 + t;
            int v = h[idx], incl = v;
            for (int d2 = 1; d2 < 64; d2 <<= 1) {
                int o = __shfl_up(incl, d2);
                if (t >= d2) incl += o;
            }
            loff[idx] = carry + incl - v;
            carry += __shfl(incl, 63);
        }
    }
    __syncthreads();
    {   // rotate bucket ownership to spread global atomics
        int rot = blockIdx.x % NB;
        for (int b0 = t; b0 < NB; b0 += PTH) {
            int bb = b0 + rot; if (bb >= NB) bb -= NB;
            gbase[bb] = bb * CAPB + atomicAdd(&bcnt[bb], h[bb]);
        }
    }
    __syncthreads();
#pragma unroll
    for (int i = 0; i < EPT; ++i) {
        int d = dreg[i];
        if (d >= 0) {
            int e = e0 + i * PTH + t;
            int s = src[e];
            int bk = d >> 7;
            int r = atomicAdd(&cur[bk], 1);
            int p = loff[bk] + r;
            stage[p] = ((u32)(d & 127) << 17) | (u32)s;
            sbid[p] = (u16)bk;
        }
    }
    __syncthreads();
    for (int i = t; i < cnt; i += PTH) {        // coalesced runs per bucket
        int bk = sbid[i];
        ebuf[gbase[bk] + (i - loff[bk])] = stage[i];
    }
}

// ---- 2. per-bucket (128 nodes) CSR build + offs/degc; in-place over ebuf ----
__global__ __launch_bounds__(512) void csrb_kernel(u32* ebuf,
                                                   const int* __restrict__ bcnt,
                                                   int* __restrict__ offs,
                                                   int* __restrict__ degc,
                                                   int N) {
    __shared__ u32 stage[CAPB];   // 19 KB
    __shared__ int h2[128], lofs[128], cur2[128];
    int t = threadIdx.x;
    int b = blockIdx.x;
    int base = b << 7;
    int e0 = b * CAPB;
    int cnt = bcnt[b];
    if (cnt > CAPB) cnt = CAPB;   // statistically unreachable clamp
    if (t < 128) { h2[t] = 0; cur2[t] = 0; }
    __syncthreads();
    for (int e = t; e < cnt; e += 512) atomicAdd(&h2[(int)(ebuf[e0 + e] >> 17)], 1);
    __syncthreads();
    if (t < 64) {
        int carry = 0;
        for (int c = 0; c < 2; ++c) {
            int idx = c * 64 + t;
            int v = h2[idx], incl = v;
            for (int d2 = 1; d2 < 64; d2 <<= 1) {
                int o = __shfl_up(incl, d2);
                if (t >= d2) incl += o;
            }
            lofs[idx] = carry + incl - v;
            carry += __shfl(incl, 63);
        }
    }
    __syncthreads();
    if (t < 128) {
        int n = base + t;
        if (n < N) { offs[n] = e0 + lofs[t]; degc[n] = h2[t]; }
    }
    for (int e = t; e < cnt; e += 512) {
        u32 pk = ebuf[e0 + e];
        int dl = (int)(pk >> 17);
        int r = atomicAdd(&cur2[dl], 1);
        stage[lofs[dl] + r] = pk & 0x1FFFF;
    }
    __syncthreads();
    for (int e = t; e < cnt; e += 512) ebuf[e0 + e] = stage[e];
}

// ---- 3. g = dinv * (x @ W1^T) via MFMA; frags direct from global ----
// wave w: nodes n0..n0+15; A lane l: x[n0+(l&15)][ks*32+(l>>4)*8..+8]
// B lane l: W1[(ct*16+(l&15))][ks*32+(l>>4)*8..+8] cvt'd in-register
// D: col=lane&15 (channel), row=(lane>>4)*4+reg (node)
__global__ __launch_bounds__(256) void gemm_kernel(const float* __restrict__ x,
                                                   const float* __restrict__ W1,
                                                   const int* __restrict__ degc,
                                                   u16* __restrict__ gb, int N) {
    int t = threadIdx.x;
    int lane = t & 63;
    int wv = t >> 6;
    int n0 = blockIdx.x * 64 + wv * 16;
    int r = lane & 15;
    int g = lane >> 4;

    int nr = n0 + r; if (nr >= N) nr = N - 1;      // clamp: garbage rows unused
    const float* xrow = x + (size_t)nr * 128 + g * 8;
    bf16x8 afr[4];
#pragma unroll
    for (int ks = 0; ks < 4; ++ks) {
        float4 lo = *(const float4*)(xrow + ks * 32);
        float4 hi = *(const float4*)(xrow + ks * 32 + 4);
        afr[ks] = pack8(lo, hi);
    }

    f32x4 acc[4] = {f32x4{0.f,0.f,0.f,0.f}, f32x4{0.f,0.f,0.f,0.f},
                    f32x4{0.f,0.f,0.f,0.f}, f32x4{0.f,0.f,0.f,0.f}};
#pragma unroll
    for (int ct = 0; ct < 4; ++ct) {
        const float* wrow = W1 + (size_t)(ct * 16 + r) * 128 + g * 8;
#pragma unroll
        for (int ks = 0; ks < 4; ++ks) {
            float4 wlo = *(const float4*)(wrow + ks * 32);
            float4 whi = *(const float4*)(wrow + ks * 32 + 4);
            bf16x8 bfr = pack8(wlo, whi);
            acc[ct] = __builtin_amdgcn_mfma_f32_16x16x32_bf16(afr[ks], bfr, acc[ct], 0, 0, 0);
        }
    }

#pragma unroll
    for (int reg = 0; reg < 4; ++reg) {
        int n = n0 + g * 4 + reg;
        if (n < N) {
            float dv = rsqrtf((float)(degc[n] + 1));
#pragma unroll
            for (int ct = 0; ct < 4; ++ct)
                gb[(size_t)n * 64 + ct * 16 + r] = (u16)f2bf(dv * acc[ct][reg]);
        }
    }
}

// ---- 4. wave per node: s_load_dwordx16 indices, 16 gathers in flight ----
__global__ __launch_bounds__(256) void agg_kernel(const u16* __restrict__ gb,
                                                  const int* __restrict__ csr,
                                                  const int* __restrict__ offs,
                                                  const int* __restrict__ degc,
                                                  const float* __restrict__ W2,
                                                  const float* __restrict__ b1,
                                                  const float* __restrict__ b2,
                                                  float* __restrict__ out, int N) {
    int wid = blockIdx.x * 4 + (threadIdx.x >> 6);
    int lane = threadIdx.x & 63;
    if (wid >= N) return;
    // wave-uniform scalars -> SGPR: csr reads become s_load, row base SALU
    int off = __builtin_amdgcn_readfirstlane(offs[wid]);
    int cnt = __builtin_amdgcn_readfirstlane(degc[wid]);
    const u16* gbl = gb + lane;               // per-lane channel base
    float acc = bf2f(gbl[(size_t)wid * 64]);  // self loop
    int j = 0;
    for (; j + 16 <= cnt; j += 16) {
        float v[16];
#pragma unroll
        for (int k = 0; k < 16; ++k) {
            int s = csr[off + j + k];         // uniform addr -> s_load_dwordx16
            v[k] = bf2f(gbl[(size_t)s * 64]);
        }
        float s01 = (v[0] + v[1]) + (v[2] + v[3]);
        float s23 = (v[4] + v[5]) + (v[6] + v[7]);
        float s45 = (v[8] + v[9]) + (v[10] + v[11]);
        float s67 = (v[12] + v[13]) + (v[14] + v[15]);
        acc += (s01 + s23) + (s45 + s67);
    }
    for (; j + 4 <= cnt; j += 4) {
        float v[4];
#pragma unroll
        for (int k = 0; k < 4; ++k) {
            int s = csr[off + j + k];
            v[k] = bf2f(gbl[(size_t)s * 64]);
        }
        acc += (v[0] + v[1]) + (v[2] + v[3]);
    }
    for (; j < cnt; ++j) {
        int s = csr[off + j];
        acc += bf2f(gbl[(size_t)s * 64]);
    }
    float dv = rsqrtf((float)(cnt + 1));
    float val = fmaxf(dv * acc + b1[lane], 0.f) * W2[lane];
#pragma unroll
    for (int o = 32; o >= 1; o >>= 1) val += __shfl_xor(val, o);
    if (lane == 0) out[wid] = val + b2[0];
}

extern "C" void kernel_launch(void* const* d_in, const int* in_sizes, int n_in,
                              void* d_out, int out_size, void* d_ws, size_t ws_size,
                              hipStream_t stream) {
    const float* x  = (const float*)d_in[0];
    const int*   ei = (const int*)d_in[1];
    const float* W1 = (const float*)d_in[2];
    const float* b1 = (const float*)d_in[3];
    const float* W2 = (const float*)d_in[4];
    const float* b2 = (const float*)d_in[5];
    float* out = (float*)d_out;

    int N = in_sizes[0] / 128;
    int E = in_sizes[1] / 2;
    const int* src = ei;
    const int* dst = ei + E;
    int NB = (N + 127) >> 7;           // 782 (<= NBMAX)
    int NBLK = (E + PK - 1) / PK;      // 782

    char* ws = (char*)d_ws;
    int* bcnt = (int*)(ws + 0x000000);   // NB ints
    int* degc = (int*)(ws + 0x010000);   // N ints
    int* offs = (int*)(ws + 0x080000);   // N ints
    u32* ebuf = (u32*)(ws + 0x100000);   // NB*CAPB u32 (15.2 MB); becomes csr
    u16* gb   = (u16*)(ws + 0x1000000);  // N*64 bf16 (12.8 MB) -> ends ~28.8 MB

    hipMemsetAsync(bcnt, 0, (size_t)NB * 4, stream);
    part_kernel<<<NBLK, PTH, 0, stream>>>(src, dst, bcnt, ebuf, E, NB);
    csrb_kernel<<<NB, 512, 0, stream>>>(ebuf, bcnt, offs, degc, N);
    gemm_kernel<<<(N + 63) / 64, 256, 0, stream>>>(x, W1, degc, gb, N);
    agg_kernel<<<(N + 3) / 4, 256, 0, stream>>>(gb, (const int*)ebuf, offs, degc, W2, b1, b2, out, N);
}

// Round 22
// 131.299 us; speedup vs baseline: 1.1426x; 1.1426x over previous
//
#include <hip/hip_runtime.h>
#include <hip/hip_bf16.h>

// GCN regression: out = relu( dinv⊙(A_hat @ (dinv⊙(x@W1^T))) + b1 ) @ W2^T + b2
// R17: R14 structure (slotted CSR, 5 dispatches) + R13's 16-deep agg.
//   1. setup_kernel : bcnt=0  +  W1 f32->bf16
//   2. part_kernel  : per-block(4096 edges) LDS hist + scan + 1 atomic/bucket
//                     -> slotted ebuf (bucket b at b*CAPB)
//   3. csrb2_kernel : per-bucket node hist+scan (offs/degc), LDS scatter ->
//                     slotted csr span
//   4. gemm_kernel  : g = dinv ⊙ (x @ W1^T) via mfma_f32_16x16x32_bf16
//   5. agg_kernel   : wave per node; s_load csr indices; 16 gathers in flight

typedef unsigned int u32;
typedef unsigned short u16;
typedef __attribute__((ext_vector_type(8))) short bf16x8;
typedef __attribute__((ext_vector_type(4))) float f32x4;

#define PK 4096      // edges per partition block
#define PTH 512      // part threads
#define EPT (PK/PTH) // 8
#define CAPB 9216    // slot capacity per 256-node bucket (mean 8184, +11 sigma)

__device__ __forceinline__ short f2bf(float f) {   // RNE via hardware cvt
    __hip_bfloat16 h = __float2bfloat16(f);
    return *reinterpret_cast<short*>(&h);
}
__device__ __forceinline__ float bf2f(u16 u) {
    return __uint_as_float(((u32)u) << 16);
}
__device__ __forceinline__ bf16x8 pack8(float4 lo, float4 hi) {
    bf16x8 o;
    o[0] = f2bf(lo.x); o[1] = f2bf(lo.y); o[2] = f2bf(lo.z); o[3] = f2bf(lo.w);
    o[4] = f2bf(hi.x); o[5] = f2bf(hi.y); o[6] = f2bf(hi.z); o[7] = f2bf(hi.w);
    return o;
}

// ---- 1. setup: zero bucket counts + W1 -> bf16 ----
__global__ __launch_bounds__(512) void setup_kernel(int* __restrict__ bcnt,
                                                    const float* __restrict__ W1,
                                                    u16* __restrict__ wbf, int NB) {
    int t = threadIdx.x;
    if (blockIdx.x == 0) {
        if (t < NB) bcnt[t] = 0;
    } else {
#pragma unroll
        for (int i = 0; i < 16; ++i) wbf[i * 512 + t] = (u16)f2bf(W1[i * 512 + t]);
    }
}

// ---- 2. chunked partition -> slotted ebuf ----
__global__ __launch_bounds__(PTH) void part_kernel(const int* __restrict__ src,
                                                   const int* __restrict__ dst,
                                                   int* __restrict__ bcnt,
                                                   u32* __restrict__ ebuf, int E, int NB) {
    __shared__ u32 stage[PK];     // 16 KB
    __shared__ u16 sbid[PK];      // 8 KB
    __shared__ int h[512], loff[512], gbase[512], cur[512];   // 8 KB
    int t = threadIdx.x;
    int e0 = blockIdx.x * PK;
    int e1 = e0 + PK; if (e1 > E) e1 = E;
    int cnt = e1 - e0;
    h[t] = 0; cur[t] = 0;
    __syncthreads();
    int dreg[EPT];
#pragma unroll
    for (int i = 0; i < EPT; ++i) {
        int e = e0 + i * PTH + t;
        dreg[i] = (e < e1) ? dst[e] : -1;
        if (dreg[i] >= 0) atomicAdd(&h[dreg[i] >> 8], 1);
    }
    __syncthreads();
    if (t < 64) {                 // wave 0: scan 512 slots, carry across chunks
        int carry = 0;
        for (int c = 0; c < 8; ++c) {
            int idx = c * 64 + t;
            int v = h[idx], incl = v;
            for (int d2 = 1; d2 < 64; d2 <<= 1) {
                int o = __shfl_up(incl, d2);
                if (t >= d2) incl += o;
            }
            loff[idx] = carry + incl - v;
            carry += __shfl(incl, 63);
        }
    }
    __syncthreads();
    if (t < NB) gbase[t] = t * CAPB + atomicAdd(&bcnt[t], h[t]);
    __syncthreads();
#pragma unroll
    for (int i = 0; i < EPT; ++i) {
        int d = dreg[i];
        if (d >= 0) {
            int e = e0 + i * PTH + t;
            int s = src[e];
            int bk = d >> 8;
            int r = atomicAdd(&cur[bk], 1);
            int p = loff[bk] + r;
            stage[p] = ((u32)(d & 255) << 17) | (u32)s;
            sbid[p] = (u16)bk;
        }
    }
    __syncthreads();
    for (int i = t; i < cnt; i += PTH) {        // coalesced runs per bucket
        int bk = sbid[i];
        ebuf[gbase[bk] + (i - loff[bk])] = stage[i];
    }
}

// ---- 3. per-bucket CSR build (slotted) + offs/degc (512 threads) ----
__global__ __launch_bounds__(512) void csrb2_kernel(const u32* __restrict__ ebuf,
                                                    const int* __restrict__ bcnt,
                                                    int* __restrict__ csr,
                                                    int* __restrict__ offs,
                                                    int* __restrict__ degc,
                                                    int N) {
    __shared__ u32 stage[CAPB];   // 36 KB
    __shared__ int h2[256], lofs[256], cur2[256];
    int t = threadIdx.x;
    int b = blockIdx.x;
    int base = b << 8;
    int e0 = b * CAPB;
    int cnt = bcnt[b];
    if (t < 256) { h2[t] = 0; cur2[t] = 0; }
    __syncthreads();
    for (int e = t; e < cnt; e += 512) atomicAdd(&h2[(int)(ebuf[e0 + e] >> 17)], 1);
    __syncthreads();
    if (t < 64) {
        int carry = 0;
        for (int c = 0; c < 4; ++c) {
            int idx = c * 64 + t;
            int v = h2[idx], incl = v;
            for (int d2 = 1; d2 < 64; d2 <<= 1) {
                int o = __shfl_up(incl, d2);
                if (t >= d2) incl += o;
            }
            lofs[idx] = carry + incl - v;
            carry += __shfl(incl, 63);
        }
    }
    __syncthreads();
    if (t < 256) {
        int n = base + t;
        if (n < N) { offs[n] = e0 + lofs[t]; degc[n] = h2[t]; }
    }
    if (cnt <= CAPB) {
        for (int e = t; e < cnt; e += 512) {
            u32 pk = ebuf[e0 + e];
            int dl = (int)(pk >> 17);
            int r = atomicAdd(&cur2[dl], 1);
            stage[lofs[dl] + r] = pk & 0x1FFFF;
        }
        __syncthreads();
        for (int e = t; e < cnt; e += 512) csr[e0 + e] = (int)stage[e];
    } else {  // statistically unreachable fallback
        for (int e = t; e < cnt; e += 512) {
            u32 pk = ebuf[e0 + e];
            int dl = (int)(pk >> 17);
            int r = atomicAdd(&cur2[dl], 1);
            csr[e0 + lofs[dl] + r] = (int)(pk & 0x1FFFF);
        }
    }
}

// ---- 4. g = dinv * (x @ W1^T) via MFMA; frags direct from global ----
// wave w: nodes n0..n0+15; A lane l: x[n0+(l&15)][ks*32+(l>>4)*8..+8]
// B lane l: wbf[(ct*16+(l&15))*128 + ks*32+(l>>4)*8..+8]
// D: col=lane&15 (channel), row=(lane>>4)*4+reg (node)
__global__ __launch_bounds__(256) void gemm_kernel(const float* __restrict__ x,
                                                   const u16* __restrict__ wbf,
                                                   const int* __restrict__ degc,
                                                   u16* __restrict__ gb, int N) {
    int t = threadIdx.x;
    int lane = t & 63;
    int wv = t >> 6;
    int n0 = blockIdx.x * 64 + wv * 16;
    int r = lane & 15;
    int g = lane >> 4;

    int nr = n0 + r; if (nr >= N) nr = N - 1;      // clamp: garbage rows unused
    const float* xrow = x + (size_t)nr * 128 + g * 8;
    bf16x8 afr[4];
#pragma unroll
    for (int ks = 0; ks < 4; ++ks) {
        float4 lo = *(const float4*)(xrow + ks * 32);
        float4 hi = *(const float4*)(xrow + ks * 32 + 4);
        afr[ks] = pack8(lo, hi);
    }

    f32x4 acc[4] = {f32x4{0.f,0.f,0.f,0.f}, f32x4{0.f,0.f,0.f,0.f},
                    f32x4{0.f,0.f,0.f,0.f}, f32x4{0.f,0.f,0.f,0.f}};
#pragma unroll
    for (int ct = 0; ct < 4; ++ct) {
        const u16* wrow = wbf + (ct * 16 + r) * 128 + g * 8;
#pragma unroll
        for (int ks = 0; ks < 4; ++ks) {
            bf16x8 bfr = *(const bf16x8*)(wrow + ks * 32);
            acc[ct] = __builtin_amdgcn_mfma_f32_16x16x32_bf16(afr[ks], bfr, acc[ct], 0, 0, 0);
        }
    }

#pragma unroll
    for (int reg = 0; reg < 4; ++reg) {
        int n = n0 + g * 4 + reg;
        if (n < N) {
            float dv = rsqrtf((float)(degc[n] + 1));
#pragma unroll
            for (int ct = 0; ct < 4; ++ct)
                gb[(size_t)n * 64 + ct * 16 + r] = (u16)f2bf(dv * acc[ct][reg]);
        }
    }
}

// ---- 5. wave per node: s_load_dwordx16 indices, 16 gathers in flight ----
__global__ __launch_bounds__(256) void agg_kernel(const u16* __restrict__ gb,
                                                  const int* __restrict__ csr,
                                                  const int* __restrict__ offs,
                                                  const int* __restrict__ degc,
                                                  const float* __restrict__ W2,
                                                  const float* __restrict__ b1,
                                                  const float* __restrict__ b2,
                                                  float* __restrict__ out, int N) {
    int wid = blockIdx.x * 4 + (threadIdx.x >> 6);
    int lane = threadIdx.x & 63;
    if (wid >= N) return;
    // wave-uniform scalars -> SGPR: csr reads become s_load, row base SALU
    int off = __builtin_amdgcn_readfirstlane(offs[wid]);
    int cnt = __builtin_amdgcn_readfirstlane(degc[wid]);
    const u16* gbl = gb + lane;               // per-lane channel base
    float acc = bf2f(gbl[(size_t)wid * 64]);  // self loop
    int j = 0;
    for (; j + 16 <= cnt; j += 16) {
        float v[16];
#pragma unroll
        for (int k = 0; k < 16; ++k) {
            int s = csr[off + j + k];         // uniform addr -> s_load_dwordx16
            v[k] = bf2f(gbl[(size_t)s * 64]);
        }
        float s01 = (v[0] + v[1]) + (v[2] + v[3]);
        float s23 = (v[4] + v[5]) + (v[6] + v[7]);
        float s45 = (v[8] + v[9]) + (v[10] + v[11]);
        float s67 = (v[12] + v[13]) + (v[14] + v[15]);
        acc += (s01 + s23) + (s45 + s67);
    }
    for (; j + 4 <= cnt; j += 4) {
        float v[4];
#pragma unroll
        for (int k = 0; k < 4; ++k) {
            int s = csr[off + j + k];
            v[k] = bf2f(gbl[(size_t)s * 64]);
        }
        acc += (v[0] + v[1]) + (v[2] + v[3]);
    }
    for (; j < cnt; ++j) {
        int s = csr[off + j];
        acc += bf2f(gbl[(size_t)s * 64]);
    }
    float dv = rsqrtf((float)(cnt + 1));
    float val = fmaxf(dv * acc + b1[lane], 0.f) * W2[lane];
#pragma unroll
    for (int o = 32; o >= 1; o >>= 1) val += __shfl_xor(val, o);
    if (lane == 0) out[wid] = val + b2[0];
}

extern "C" void kernel_launch(void* const* d_in, const int* in_sizes, int n_in,
                              void* d_out, int out_size, void* d_ws, size_t ws_size,
                              hipStream_t stream) {
    const float* x  = (const float*)d_in[0];
    const int*   ei = (const int*)d_in[1];
    const float* W1 = (const float*)d_in[2];
    const float* b1 = (const float*)d_in[3];
    const float* W2 = (const float*)d_in[4];
    const float* b2 = (const float*)d_in[5];
    float* out = (float*)d_out;

    int N = in_sizes[0] / 128;
    int E = in_sizes[1] / 2;
    const int* src = ei;
    const int* dst = ei + E;
    int NB = (N + 255) >> 8;           // 391 (<= 512)
    int NBLK = (E + PK - 1) / PK;      // 782

    char* ws = (char*)d_ws;
    int* bcnt = (int*)(ws + 0x000000);   // NB ints
    int* degc = (int*)(ws + 0x010000);   // N ints
    int* offs = (int*)(ws + 0x080000);   // N ints
    u16* wbf  = (u16*)(ws + 0x0F0000);   // 64*128 bf16 (16 KB)
    u32* ebuf = (u32*)(ws + 0x100000);   // NB*CAPB u32 (14.4 MB); dead after csrb2
    u16* gb   = (u16*)(ws + 0x100000);   // N*64 bf16 (12.8 MB) ALIASES ebuf
    int* csr  = (int*)(ws + 0xF80000);   // NB*CAPB ints (14.4 MB) -> ends ~30 MB

    setup_kernel<<<2, 512, 0, stream>>>(bcnt, W1, wbf, NB);
    part_kernel<<<NBLK, PTH, 0, stream>>>(src, dst, bcnt, ebuf, E, NB);
    csrb2_kernel<<<NB, 512, 0, stream>>>(ebuf, bcnt, csr, offs, degc, N);
    gemm_kernel<<<(N + 63) / 64, 256, 0, stream>>>(x, wbf, degc, gb, N);
    agg_kernel<<<(N + 3) / 4, 256, 0, stream>>>(gb, csr, offs, degc, W2, b1, b2, out, N);
}

// Round 23
// 124.892 us; speedup vs baseline: 1.2012x; 1.0513x over previous
//
#include <hip/hip_runtime.h>
#include <hip/hip_bf16.h>

// GCN regression: out = relu( dinv⊙(A_hat @ (dinv⊙(x@W1^T))) + b1 ) @ W2^T + b2
// R18: R17 with part PK 8192 / 512 threads (half the global atomics, full-line
//      ebuf runs, same 2-blocks/CU occupancy on 160KB LDS).
//   1. setup_kernel : bcnt=0  +  W1 f32->bf16
//   2. part_kernel  : per-block(8192 edges) LDS hist + scan + 1 atomic/bucket
//                     -> slotted ebuf (bucket b at b*CAPB)
//   3. csrb2_kernel : per-bucket node hist+scan (offs/degc), LDS scatter ->
//                     slotted csr span
//   4. gemm_kernel  : g = dinv ⊙ (x @ W1^T) via mfma_f32_16x16x32_bf16
//   5. agg_kernel   : wave per node; s_load csr indices; 16 gathers in flight

typedef unsigned int u32;
typedef unsigned short u16;
typedef __attribute__((ext_vector_type(8))) short bf16x8;
typedef __attribute__((ext_vector_type(4))) float f32x4;

#define PK 8192      // edges per partition block
#define PTH 512      // part threads
#define EPT (PK/PTH) // 16
#define CAPB 9216    // slot capacity per 256-node bucket (mean 8184, +11 sigma)

__device__ __forceinline__ short f2bf(float f) {   // RNE via hardware cvt
    __hip_bfloat16 h = __float2bfloat16(f);
    return *reinterpret_cast<short*>(&h);
}
__device__ __forceinline__ float bf2f(u16 u) {
    return __uint_as_float(((u32)u) << 16);
}
__device__ __forceinline__ bf16x8 pack8(float4 lo, float4 hi) {
    bf16x8 o;
    o[0] = f2bf(lo.x); o[1] = f2bf(lo.y); o[2] = f2bf(lo.z); o[3] = f2bf(lo.w);
    o[4] = f2bf(hi.x); o[5] = f2bf(hi.y); o[6] = f2bf(hi.z); o[7] = f2bf(hi.w);
    return o;
}

// ---- 1. setup: zero bucket counts + W1 -> bf16 ----
__global__ __launch_bounds__(512) void setup_kernel(int* __restrict__ bcnt,
                                                    const float* __restrict__ W1,
                                                    u16* __restrict__ wbf, int NB) {
    int t = threadIdx.x;
    if (blockIdx.x == 0) {
        if (t < NB) bcnt[t] = 0;
    } else {
#pragma unroll
        for (int i = 0; i < 16; ++i) wbf[i * 512 + t] = (u16)f2bf(W1[i * 512 + t]);
    }
}

// ---- 2. chunked partition -> slotted ebuf ----
__global__ __launch_bounds__(PTH) void part_kernel(const int* __restrict__ src,
                                                   const int* __restrict__ dst,
                                                   int* __restrict__ bcnt,
                                                   u32* __restrict__ ebuf, int E, int NB) {
    __shared__ u32 stage[PK];     // 32 KB
    __shared__ u16 sbid[PK];      // 16 KB
    __shared__ int h[512], loff[512], gbase[512], cur[512];   // 8 KB (56 total)
    int t = threadIdx.x;
    int e0 = blockIdx.x * PK;
    int e1 = e0 + PK; if (e1 > E) e1 = E;
    int cnt = e1 - e0;
    h[t] = 0; cur[t] = 0;
    __syncthreads();
    int dreg[EPT];
#pragma unroll
    for (int i = 0; i < EPT; ++i) {
        int e = e0 + i * PTH + t;
        dreg[i] = (e < e1) ? dst[e] : -1;
        if (dreg[i] >= 0) atomicAdd(&h[dreg[i] >> 8], 1);
    }
    __syncthreads();
    if (t < 64) {                 // wave 0: scan 512 slots, carry across chunks
        int carry = 0;
        for (int c = 0; c < 8; ++c) {
            int idx = c * 64 + t;
            int v = h[idx], incl = v;
            for (int d2 = 1; d2 < 64; d2 <<= 1) {
                int o = __shfl_up(incl, d2);
                if (t >= d2) incl += o;
            }
            loff[idx] = carry + incl - v;
            carry += __shfl(incl, 63);
        }
    }
    __syncthreads();
    if (t < NB) gbase[t] = t * CAPB + atomicAdd(&bcnt[t], h[t]);
    __syncthreads();
#pragma unroll
    for (int i = 0; i < EPT; ++i) {
        int d = dreg[i];
        if (d >= 0) {
            int e = e0 + i * PTH + t;
            int s = src[e];
            int bk = d >> 8;
            int r = atomicAdd(&cur[bk], 1);
            int p = loff[bk] + r;
            stage[p] = ((u32)(d & 255) << 17) | (u32)s;
            sbid[p] = (u16)bk;
        }
    }
    __syncthreads();
    for (int i = t; i < cnt; i += PTH) {        // coalesced runs per bucket
        int bk = sbid[i];
        ebuf[gbase[bk] + (i - loff[bk])] = stage[i];
    }
}

// ---- 3. per-bucket CSR build (slotted) + offs/degc (512 threads) ----
__global__ __launch_bounds__(512) void csrb2_kernel(const u32* __restrict__ ebuf,
                                                    const int* __restrict__ bcnt,
                                                    int* __restrict__ csr,
                                                    int* __restrict__ offs,
                                                    int* __restrict__ degc,
                                                    int N) {
    __shared__ u32 stage[CAPB];   // 36 KB
    __shared__ int h2[256], lofs[256], cur2[256];
    int t = threadIdx.x;
    int b = blockIdx.x;
    int base = b << 8;
    int e0 = b * CAPB;
    int cnt = bcnt[b];
    if (t < 256) { h2[t] = 0; cur2[t] = 0; }
    __syncthreads();
    for (int e = t; e < cnt; e += 512) atomicAdd(&h2[(int)(ebuf[e0 + e] >> 17)], 1);
    __syncthreads();
    if (t < 64) {
        int carry = 0;
        for (int c = 0; c < 4; ++c) {
            int idx = c * 64 + t;
            int v = h2[idx], incl = v;
            for (int d2 = 1; d2 < 64; d2 <<= 1) {
                int o = __shfl_up(incl, d2);
                if (t >= d2) incl += o;
            }
            lofs[idx] = carry + incl - v;
            carry += __shfl(incl, 63);
        }
    }
    __syncthreads();
    if (t < 256) {
        int n = base + t;
        if (n < N) { offs[n] = e0 + lofs[t]; degc[n] = h2[t]; }
    }
    if (cnt <= CAPB) {
        for (int e = t; e < cnt; e += 512) {
            u32 pk = ebuf[e0 + e];
            int dl = (int)(pk >> 17);
            int r = atomicAdd(&cur2[dl], 1);
            stage[lofs[dl] + r] = pk & 0x1FFFF;
        }
        __syncthreads();
        for (int e = t; e < cnt; e += 512) csr[e0 + e] = (int)stage[e];
    } else {  // statistically unreachable fallback
        for (int e = t; e < cnt; e += 512) {
            u32 pk = ebuf[e0 + e];
            int dl = (int)(pk >> 17);
            int r = atomicAdd(&cur2[dl], 1);
            csr[e0 + lofs[dl] + r] = (int)(pk & 0x1FFFF);
        }
    }
}

// ---- 4. g = dinv * (x @ W1^T) via MFMA; frags direct from global ----
// wave w: nodes n0..n0+15; A lane l: x[n0+(l&15)][ks*32+(l>>4)*8..+8]
// B lane l: wbf[(ct*16+(l&15))*128 + ks*32+(l>>4)*8..+8]
// D: col=lane&15 (channel), row=(lane>>4)*4+reg (node)
__global__ __launch_bounds__(256) void gemm_kernel(const float* __restrict__ x,
                                                   const u16* __restrict__ wbf,
                                                   const int* __restrict__ degc,
                                                   u16* __restrict__ gb, int N) {
    int t = threadIdx.x;
    int lane = t & 63;
    int wv = t >> 6;
    int n0 = blockIdx.x * 64 + wv * 16;
    int r = lane & 15;
    int g = lane >> 4;

    int nr = n0 + r; if (nr >= N) nr = N - 1;      // clamp: garbage rows unused
    const float* xrow = x + (size_t)nr * 128 + g * 8;
    bf16x8 afr[4];
#pragma unroll
    for (int ks = 0; ks < 4; ++ks) {
        float4 lo = *(const float4*)(xrow + ks * 32);
        float4 hi = *(const float4*)(xrow + ks * 32 + 4);
        afr[ks] = pack8(lo, hi);
    }

    f32x4 acc[4] = {f32x4{0.f,0.f,0.f,0.f}, f32x4{0.f,0.f,0.f,0.f},
                    f32x4{0.f,0.f,0.f,0.f}, f32x4{0.f,0.f,0.f,0.f}};
#pragma unroll
    for (int ct = 0; ct < 4; ++ct) {
        const u16* wrow = wbf + (ct * 16 + r) * 128 + g * 8;
#pragma unroll
        for (int ks = 0; ks < 4; ++ks) {
            bf16x8 bfr = *(const bf16x8*)(wrow + ks * 32);
            acc[ct] = __builtin_amdgcn_mfma_f32_16x16x32_bf16(afr[ks], bfr, acc[ct], 0, 0, 0);
        }
    }

#pragma unroll
    for (int reg = 0; reg < 4; ++reg) {
        int n = n0 + g * 4 + reg;
        if (n < N) {
            float dv = rsqrtf((float)(degc[n] + 1));
#pragma unroll
            for (int ct = 0; ct < 4; ++ct)
                gb[(size_t)n * 64 + ct * 16 + r] = (u16)f2bf(dv * acc[ct][reg]);
        }
    }
}

// ---- 5. wave per node: s_load_dwordx16 indices, 16 gathers in flight ----
__global__ __launch_bounds__(256) void agg_kernel(const u16* __restrict__ gb,
                                                  const int* __restrict__ csr,
                                                  const int* __restrict__ offs,
                                                  const int* __restrict__ degc,
                                                  const float* __restrict__ W2,
                                                  const float* __restrict__ b1,
                                                  const float* __restrict__ b2,
                                                  float* __restrict__ out, int N) {
    int wid = blockIdx.x * 4 + (threadIdx.x >> 6);
    int lane = threadIdx.x & 63;
    if (wid >= N) return;
    // wave-uniform scalars -> SGPR: csr reads become s_load, row base SALU
    int off = __builtin_amdgcn_readfirstlane(offs[wid]);
    int cnt = __builtin_amdgcn_readfirstlane(degc[wid]);
    const u16* gbl = gb + lane;               // per-lane channel base
    float acc = bf2f(gbl[(size_t)wid * 64]);  // self loop
    int j = 0;
    for (; j + 16 <= cnt; j += 16) {
        float v[16];
#pragma unroll
        for (int k = 0; k < 16; ++k) {
            int s = csr[off + j + k];         // uniform addr -> s_load_dwordx16
            v[k] = bf2f(gbl[(size_t)s * 64]);
        }
        float s01 = (v[0] + v[1]) + (v[2] + v[3]);
        float s23 = (v[4] + v[5]) + (v[6] + v[7]);
        float s45 = (v[8] + v[9]) + (v[10] + v[11]);
        float s67 = (v[12] + v[13]) + (v[14] + v[15]);
        acc += (s01 + s23) + (s45 + s67);
    }
    for (; j + 4 <= cnt; j += 4) {
        float v[4];
#pragma unroll
        for (int k = 0; k < 4; ++k) {
            int s = csr[off + j + k];
            v[k] = bf2f(gbl[(size_t)s * 64]);
        }
        acc += (v[0] + v[1]) + (v[2] + v[3]);
    }
    for (; j < cnt; ++j) {
        int s = csr[off + j];
        acc += bf2f(gbl[(size_t)s * 64]);
    }
    float dv = rsqrtf((float)(cnt + 1));
    float val = fmaxf(dv * acc + b1[lane], 0.f) * W2[lane];
#pragma unroll
    for (int o = 32; o >= 1; o >>= 1) val += __shfl_xor(val, o);
    if (lane == 0) out[wid] = val + b2[0];
}

extern "C" void kernel_launch(void* const* d_in, const int* in_sizes, int n_in,
                              void* d_out, int out_size, void* d_ws, size_t ws_size,
                              hipStream_t stream) {
    const float* x  = (const float*)d_in[0];
    const int*   ei = (const int*)d_in[1];
    const float* W1 = (const float*)d_in[2];
    const float* b1 = (const float*)d_in[3];
    const float* W2 = (const float*)d_in[4];
    const float* b2 = (const float*)d_in[5];
    float* out = (float*)d_out;

    int N = in_sizes[0] / 128;
    int E = in_sizes[1] / 2;
    const int* src = ei;
    const int* dst = ei + E;
    int NB = (N + 255) >> 8;           // 391 (<= 512)
    int NBLK = (E + PK - 1) / PK;      // 391

    char* ws = (char*)d_ws;
    int* bcnt = (int*)(ws + 0x000000);   // NB ints
    int* degc = (int*)(ws + 0x010000);   // N ints
    int* offs = (int*)(ws + 0x080000);   // N ints
    u16* wbf  = (u16*)(ws + 0x0F0000);   // 64*128 bf16 (16 KB)
    u32* ebuf = (u32*)(ws + 0x100000);   // NB*CAPB u32 (14.4 MB); dead after csrb2
    u16* gb   = (u16*)(ws + 0x100000);   // N*64 bf16 (12.8 MB) ALIASES ebuf
    int* csr  = (int*)(ws + 0xF80000);   // NB*CAPB ints (14.4 MB) -> ends ~30 MB

    setup_kernel<<<2, 512, 0, stream>>>(bcnt, W1, wbf, NB);
    part_kernel<<<NBLK, PTH, 0, stream>>>(src, dst, bcnt, ebuf, E, NB);
    csrb2_kernel<<<NB, 512, 0, stream>>>(ebuf, bcnt, csr, offs, degc, N);
    gemm_kernel<<<(N + 63) / 64, 256, 0, stream>>>(x, wbf, degc, gb, N);
    agg_kernel<<<(N + 3) / 4, 256, 0, stream>>>(gb, csr, offs, degc, W2, b1, b2, out, N);
}

// Round 24
// 124.862 us; speedup vs baseline: 1.2015x; 1.0002x over previous
//
#include <hip/hip_runtime.h>
#include <hip/hip_bf16.h>

// GCN regression: out = relu( dinv⊙(A_hat @ (dinv⊙(x@W1^T))) + b1 ) @ W2^T + b2
// R19: csrb2 single-pass (register-staged ebuf), setup folded into
//      memset + part block 0. 4 dispatches + memset.
//   1. part_kernel  : block0 prologue W1->bf16; per-block(8192 edges) LDS hist
//                     + scan + 1 atomic/bucket -> slotted ebuf
//   2. csrb2_kernel : per-bucket node hist+scan (offs/degc) from REGISTERS,
//                     LDS scatter -> slotted csr span
//   3. gemm_kernel  : g = dinv ⊙ (x @ W1^T) via mfma_f32_16x16x32_bf16
//   4. agg_kernel   : wave per node; s_load csr indices; 16 gathers in flight

typedef unsigned int u32;
typedef unsigned short u16;
typedef __attribute__((ext_vector_type(8))) short bf16x8;
typedef __attribute__((ext_vector_type(4))) float f32x4;

#define PK 8192      // edges per partition block
#define PTH 512      // part threads
#define EPT (PK/PTH) // 16
#define CAPB 9216    // slot capacity per 256-node bucket (mean 8184, +11 sigma)
#define ERT 18       // csrb2 regs per thread: ceil(CAPB/512)

__device__ __forceinline__ short f2bf(float f) {   // RNE via hardware cvt
    __hip_bfloat16 h = __float2bfloat16(f);
    return *reinterpret_cast<short*>(&h);
}
__device__ __forceinline__ float bf2f(u16 u) {
    return __uint_as_float(((u32)u) << 16);
}
__device__ __forceinline__ bf16x8 pack8(float4 lo, float4 hi) {
    bf16x8 o;
    o[0] = f2bf(lo.x); o[1] = f2bf(lo.y); o[2] = f2bf(lo.z); o[3] = f2bf(lo.w);
    o[4] = f2bf(hi.x); o[5] = f2bf(hi.y); o[6] = f2bf(hi.z); o[7] = f2bf(hi.w);
    return o;
}

// ---- 1. chunked partition -> slotted ebuf (block 0: W1 cvt prologue) ----
__global__ __launch_bounds__(PTH) void part_kernel(const int* __restrict__ src,
                                                   const int* __restrict__ dst,
                                                   int* __restrict__ bcnt,
                                                   u32* __restrict__ ebuf,
                                                   const float* __restrict__ W1,
                                                   u16* __restrict__ wbf,
                                                   int E, int NB) {
    __shared__ u32 stage[PK];     // 32 KB
    __shared__ u16 sbid[PK];      // 16 KB
    __shared__ int h[512], loff[512], gbase[512], cur[512];   // 8 KB (56 total)
    int t = threadIdx.x;
    if (blockIdx.x == 0) {        // prologue: W1 -> bf16 (overlapped by others)
#pragma unroll
        for (int i = 0; i < 16; ++i) wbf[i * 512 + t] = (u16)f2bf(W1[i * 512 + t]);
    }
    int e0 = blockIdx.x * PK;
    int e1 = e0 + PK; if (e1 > E) e1 = E;
    int cnt = e1 - e0;
    h[t] = 0; cur[t] = 0;
    __syncthreads();
    int dreg[EPT];
#pragma unroll
    for (int i = 0; i < EPT; ++i) {
        int e = e0 + i * PTH + t;
        dreg[i] = (e < e1) ? dst[e] : -1;
        if (dreg[i] >= 0) atomicAdd(&h[dreg[i] >> 8], 1);
    }
    __syncthreads();
    if (t < 64) {                 // wave 0: scan 512 slots, carry across chunks
        int carry = 0;
        for (int c = 0; c < 8; ++c) {
            int idx = c * 64 + t;
            int v = h[idx], incl = v;
            for (int d2 = 1; d2 < 64; d2 <<= 1) {
                int o = __shfl_up(incl, d2);
                if (t >= d2) incl += o;
            }
            loff[idx] = carry + incl - v;
            carry += __shfl(incl, 63);
        }
    }
    __syncthreads();
    if (t < NB) gbase[t] = t * CAPB + atomicAdd(&bcnt[t], h[t]);
    __syncthreads();
#pragma unroll
    for (int i = 0; i < EPT; ++i) {
        int d = dreg[i];
        if (d >= 0) {
            int e = e0 + i * PTH + t;
            int s = src[e];
            int bk = d >> 8;
            int r = atomicAdd(&cur[bk], 1);
            int p = loff[bk] + r;
            stage[p] = ((u32)(d & 255) << 17) | (u32)s;
            sbid[p] = (u16)bk;
        }
    }
    __syncthreads();
    for (int i = t; i < cnt; i += PTH) {        // coalesced runs per bucket
        int bk = sbid[i];
        ebuf[gbase[bk] + (i - loff[bk])] = stage[i];
    }
}

// ---- 2. per-bucket CSR build, single ebuf read (register-staged) ----
__global__ __launch_bounds__(512) void csrb2_kernel(const u32* __restrict__ ebuf,
                                                    const int* __restrict__ bcnt,
                                                    int* __restrict__ csr,
                                                    int* __restrict__ offs,
                                                    int* __restrict__ degc,
                                                    int N) {
    __shared__ u32 stage[CAPB];   // 36 KB
    __shared__ int h2[256], lofs[256], cur2[256];
    int t = threadIdx.x;
    int b = blockIdx.x;
    int base = b << 8;
    int e0 = b * CAPB;
    int cnt = bcnt[b];
    if (cnt > CAPB) cnt = CAPB;   // statistically unreachable clamp
    if (t < 256) { h2[t] = 0; cur2[t] = 0; }
    __syncthreads();
    u32 ereg[ERT];                // static indexing only (no scratch)
#pragma unroll
    for (int i = 0; i < ERT; ++i) {
        int e = i * 512 + t;
        ereg[i] = (e < cnt) ? ebuf[e0 + e] : 0xFFFFFFFFu;
    }
#pragma unroll
    for (int i = 0; i < ERT; ++i)
        if (ereg[i] != 0xFFFFFFFFu) atomicAdd(&h2[(int)(ereg[i] >> 17)], 1);
    __syncthreads();
    if (t < 64) {
        int carry = 0;
        for (int c = 0; c < 4; ++c) {
            int idx = c * 64 + t;
            int v = h2[idx], incl = v;
            for (int d2 = 1; d2 < 64; d2 <<= 1) {
                int o = __shfl_up(incl, d2);
                if (t >= d2) incl += o;
            }
            lofs[idx] = carry + incl - v;
            carry += __shfl(incl, 63);
        }
    }
    __syncthreads();
    if (t < 256) {
        int n = base + t;
        if (n < N) { offs[n] = e0 + lofs[t]; degc[n] = h2[t]; }
    }
#pragma unroll
    for (int i = 0; i < ERT; ++i) {
        u32 pk = ereg[i];
        if (pk != 0xFFFFFFFFu) {
            int dl = (int)(pk >> 17);
            int r = atomicAdd(&cur2[dl], 1);
            stage[lofs[dl] + r] = pk & 0x1FFFF;
        }
    }
    __syncthreads();
    for (int e = t; e < cnt; e += 512) csr[e0 + e] = (int)stage[e];
}

// ---- 3. g = dinv * (x @ W1^T) via MFMA; frags direct from global ----
// wave w: nodes n0..n0+15; A lane l: x[n0+(l&15)][ks*32+(l>>4)*8..+8]
// B lane l: wbf[(ct*16+(l&15))*128 + ks*32+(l>>4)*8..+8]
// D: col=lane&15 (channel), row=(lane>>4)*4+reg (node)
__global__ __launch_bounds__(256) void gemm_kernel(const float* __restrict__ x,
                                                   const u16* __restrict__ wbf,
                                                   const int* __restrict__ degc,
                                                   u16* __restrict__ gb, int N) {
    int t = threadIdx.x;
    int lane = t & 63;
    int wv = t >> 6;
    int n0 = blockIdx.x * 64 + wv * 16;
    int r = lane & 15;
    int g = lane >> 4;

    int nr = n0 + r; if (nr >= N) nr = N - 1;      // clamp: garbage rows unused
    const float* xrow = x + (size_t)nr * 128 + g * 8;
    bf16x8 afr[4];
#pragma unroll
    for (int ks = 0; ks < 4; ++ks) {
        float4 lo = *(const float4*)(xrow + ks * 32);
        float4 hi = *(const float4*)(xrow + ks * 32 + 4);
        afr[ks] = pack8(lo, hi);
    }

    f32x4 acc[4] = {f32x4{0.f,0.f,0.f,0.f}, f32x4{0.f,0.f,0.f,0.f},
                    f32x4{0.f,0.f,0.f,0.f}, f32x4{0.f,0.f,0.f,0.f}};
#pragma unroll
    for (int ct = 0; ct < 4; ++ct) {
        const u16* wrow = wbf + (ct * 16 + r) * 128 + g * 8;
#pragma unroll
        for (int ks = 0; ks < 4; ++ks) {
            bf16x8 bfr = *(const bf16x8*)(wrow + ks * 32);
            acc[ct] = __builtin_amdgcn_mfma_f32_16x16x32_bf16(afr[ks], bfr, acc[ct], 0, 0, 0);
        }
    }

#pragma unroll
    for (int reg = 0; reg < 4; ++reg) {
        int n = n0 + g * 4 + reg;
        if (n < N) {
            float dv = rsqrtf((float)(degc[n] + 1));
#pragma unroll
            for (int ct = 0; ct < 4; ++ct)
                gb[(size_t)n * 64 + ct * 16 + r] = (u16)f2bf(dv * acc[ct][reg]);
        }
    }
}

// ---- 4. wave per node: s_load_dwordx16 indices, 16 gathers in flight ----
__global__ __launch_bounds__(256) void agg_kernel(const u16* __restrict__ gb,
                                                  const int* __restrict__ csr,
                                                  const int* __restrict__ offs,
                                                  const int* __restrict__ degc,
                                                  const float* __restrict__ W2,
                                                  const float* __restrict__ b1,
                                                  const float* __restrict__ b2,
                                                  float* __restrict__ out, int N) {
    int wid = blockIdx.x * 4 + (threadIdx.x >> 6);
    int lane = threadIdx.x & 63;
    if (wid >= N) return;
    // wave-uniform scalars -> SGPR: csr reads become s_load, row base SALU
    int off = __builtin_amdgcn_readfirstlane(offs[wid]);
    int cnt = __builtin_amdgcn_readfirstlane(degc[wid]);
    const u16* gbl = gb + lane;               // per-lane channel base
    float acc = bf2f(gbl[(size_t)wid * 64]);  // self loop
    int j = 0;
    for (; j + 16 <= cnt; j += 16) {
        float v[16];
#pragma unroll
        for (int k = 0; k < 16; ++k) {
            int s = csr[off + j + k];         // uniform addr -> s_load_dwordx16
            v[k] = bf2f(gbl[(size_t)s * 64]);
        }
        float s01 = (v[0] + v[1]) + (v[2] + v[3]);
        float s23 = (v[4] + v[5]) + (v[6] + v[7]);
        float s45 = (v[8] + v[9]) + (v[10] + v[11]);
        float s67 = (v[12] + v[13]) + (v[14] + v[15]);
        acc += (s01 + s23) + (s45 + s67);
    }
    for (; j + 4 <= cnt; j += 4) {
        float v[4];
#pragma unroll
        for (int k = 0; k < 4; ++k) {
            int s = csr[off + j + k];
            v[k] = bf2f(gbl[(size_t)s * 64]);
        }
        acc += (v[0] + v[1]) + (v[2] + v[3]);
    }
    for (; j < cnt; ++j) {
        int s = csr[off + j];
        acc += bf2f(gbl[(size_t)s * 64]);
    }
    float dv = rsqrtf((float)(cnt + 1));
    float val = fmaxf(dv * acc + b1[lane], 0.f) * W2[lane];
#pragma unroll
    for (int o = 32; o >= 1; o >>= 1) val += __shfl_xor(val, o);
    if (lane == 0) out[wid] = val + b2[0];
}

extern "C" void kernel_launch(void* const* d_in, const int* in_sizes, int n_in,
                              void* d_out, int out_size, void* d_ws, size_t ws_size,
                              hipStream_t stream) {
    const float* x  = (const float*)d_in[0];
    const int*   ei = (const int*)d_in[1];
    const float* W1 = (const float*)d_in[2];
    const float* b1 = (const float*)d_in[3];
    const float* W2 = (const float*)d_in[4];
    const float* b2 = (const float*)d_in[5];
    float* out = (float*)d_out;

    int N = in_sizes[0] / 128;
    int E = in_sizes[1] / 2;
    const int* src = ei;
    const int* dst = ei + E;
    int NB = (N + 255) >> 8;           // 391 (<= 512)
    int NBLK = (E + PK - 1) / PK;      // 391

    char* ws = (char*)d_ws;
    int* bcnt = (int*)(ws + 0x000000);   // NB ints
    int* degc = (int*)(ws + 0x010000);   // N ints
    int* offs = (int*)(ws + 0x080000);   // N ints
    u16* wbf  = (u16*)(ws + 0x0F0000);   // 64*128 bf16 (16 KB)
    u32* ebuf = (u32*)(ws + 0x100000);   // NB*CAPB u32 (14.4 MB); dead after csrb2
    u16* gb   = (u16*)(ws + 0x100000);   // N*64 bf16 (12.8 MB) ALIASES ebuf
    int* csr  = (int*)(ws + 0xF80000);   // NB*CAPB ints (14.4 MB) -> ends ~30 MB

    hipMemsetAsync(bcnt, 0, (size_t)NB * 4, stream);
    part_kernel<<<NBLK, PTH, 0, stream>>>(src, dst, bcnt, ebuf, W1, wbf, E, NB);
    csrb2_kernel<<<NB, 512, 0, stream>>>(ebuf, bcnt, csr, offs, degc, N);
    gemm_kernel<<<(N + 63) / 64, 256, 0, stream>>>(x, wbf, degc, gb, N);
    agg_kernel<<<(N + 3) / 4, 256, 0, stream>>>(gb, csr, offs, degc, W2, b1, b2, out, N);
}